// Round 2
// baseline (643.757 us; speedup 1.0000x reference)
//
#include <hip/hip_runtime.h>
#include <math.h>

// MoE gate: B=4, S=4096, H=2048, E=64, top-2, seq_aux loss.
// d_out layout (float): topk_idx [16384*2] | topk_weight [16384*2] | aux_loss [1]

#define TT 16384   // tokens
#define HH 2048
#define EE 64
#define BB 4
#define M_TOK 16   // tokens per block
#define KC 512     // k-range per wave (2048 / 4 waves)
#define TPW 4      // tokens per wave in phase 2 (M_TOK/4)

typedef float v2f __attribute__((ext_vector_type(2)));
typedef float v4f __attribute__((ext_vector_type(4)));

// packed fp32 FMA: acc = a*b + acc (2 MACs/lane/instr — needed to reach 157 TF)
__device__ __forceinline__ void pkfma(v2f& acc, v2f a, v2f b) {
    asm("v_pk_fma_f32 %0, %1, %2, %0" : "+v"(acc) : "v"(a), "v"(b));
}

// K0: W[E][H] -> Wt2 paired layout: wt2[(k/2)*64 + e] = (W[e][k], W[e][k+1])
// so a lane's packed-k weight pair is a single coalesced 8-B load.
__global__ void transpose_w(const float* __restrict__ w, v2f* __restrict__ wt2) {
    int idx = blockIdx.x * blockDim.x + threadIdx.x;  // 0..65535, e fast
    int h2 = idx >> 6, e = idx & 63;
    v2f p;
    p.x = w[e * HH + 2 * h2];
    p.y = w[e * HH + 2 * h2 + 1];
    wt2[idx] = p;
}

__global__ __launch_bounds__(256, 4) void moe_gate(
    const float* __restrict__ x, const float* __restrict__ w,
    const v2f* __restrict__ wt2,
    float* __restrict__ out_idx, float* __restrict__ out_w,
    float* __restrict__ g_cnt, float* __restrict__ g_ssum) {

    __shared__ float part[4][M_TOK][EE];   // 16 KB partial logits
    __shared__ float bssum[EE];

    const int tid  = threadIdx.x;
    const int wave = tid >> 6;
    const int lane = tid & 63;             // lane == expert in phases 1-2
    const int tok0 = blockIdx.x * M_TOK;
    const int b    = tok0 >> 12;           // batch (uniform: 16 | 4096)

    if (tid < EE) bssum[tid] = 0.f;

    // ---------- phase 1: packed fp32 partial GEMV over this wave's K-range ----
    v2f acc[M_TOK];
#pragma unroll
    for (int t = 0; t < M_TOK; ++t) { acc[t].x = 0.f; acc[t].y = 0.f; }

    const int k0 = wave * KC;
    const v2f* __restrict__ wtp = wt2 + (size_t)(k0 >> 1) * EE + lane;
    const float* __restrict__ xp = x + (size_t)tok0 * HH + k0;

    for (int kk = 0; kk < KC; kk += 8) {
        v2f wp2[4];
#pragma unroll
        for (int j = 0; j < 4; ++j) wp2[j] = wtp[(size_t)((kk >> 1) + j) * EE];
#pragma unroll
        for (int t = 0; t < M_TOK; ++t) {
            const float* __restrict__ xr = xp + (size_t)t * HH + kk;
            v4f x0 = *(const v4f*)xr;          // wave-uniform broadcast loads
            v4f x1 = *(const v4f*)(xr + 4);
            pkfma(acc[t], x0.lo, wp2[0]);
            pkfma(acc[t], x0.hi, wp2[1]);
            pkfma(acc[t], x1.lo, wp2[2]);
            pkfma(acc[t], x1.hi, wp2[3]);
        }
    }
#pragma unroll
    for (int t = 0; t < M_TOK; ++t) part[wave][t][lane] = acc[t].x + acc[t].y;
    __syncthreads();

    // ---------- phase 2+3: softmax, fp32 top-4, fp64 re-rank ----------
    float my_ssum = 0.f;  // sum of scores for expert=lane over this wave's tokens
    for (int ti = 0; ti < TPW; ++ti) {
        const int t = wave * TPW + ti;
        float logit = part[0][t][lane] + part[1][t][lane] +
                      part[2][t][lane] + part[3][t][lane];

        // softmax scores (fp32 — only feeds aux loss, loose tolerance)
        float m = logit;
#pragma unroll
        for (int off = 32; off; off >>= 1) m = fmaxf(m, __shfl_xor(m, off, 64));
        float p = __expf(logit - m);
        float Z = p;
#pragma unroll
        for (int off = 32; off; off >>= 1) Z += __shfl_xor(Z, off, 64);
        my_ssum += p / Z;

        // top-4 candidates by fp32 logit (tie -> lower index)
        float v = logit;
        int cand[4];
#pragma unroll
        for (int r = 0; r < 4; ++r) {
            float bv = v; int bi = lane;
#pragma unroll
            for (int off = 32; off; off >>= 1) {
                float ov = __shfl_xor(bv, off, 64);
                int   oi = __shfl_xor(bi, off, 64);
                if (ov > bv || (ov == bv && oi < bi)) { bv = ov; bi = oi; }
            }
            cand[r] = bi;
            if (lane == bi) v = -3.4e38f;
        }

        // fp64 re-rank: all 64 lanes cooperate; each lane covers 32 k-values
        // (float4 x 8, stride 256) for all 4 candidate experts.
        const float* __restrict__ xt  = x + (size_t)(tok0 + t) * HH;
        const float* __restrict__ w0p = w + (size_t)cand[0] * HH;
        const float* __restrict__ w1p = w + (size_t)cand[1] * HH;
        const float* __restrict__ w2p = w + (size_t)cand[2] * HH;
        const float* __restrict__ w3p = w + (size_t)cand[3] * HH;
        double d0 = 0.0, d1 = 0.0, d2 = 0.0, d3 = 0.0;
#pragma unroll
        for (int i = 0; i < 8; ++i) {
            const int k = i * 256 + lane * 4;
            v4f xv = *(const v4f*)(xt + k);
            v4f a0 = *(const v4f*)(w0p + k);
            v4f a1 = *(const v4f*)(w1p + k);
            v4f a2 = *(const v4f*)(w2p + k);
            v4f a3 = *(const v4f*)(w3p + k);
            double dx0 = (double)xv.x, dx1 = (double)xv.y;
            double dx2 = (double)xv.z, dx3 = (double)xv.w;
            d0 = fma(dx0, (double)a0.x, d0); d0 = fma(dx1, (double)a0.y, d0);
            d0 = fma(dx2, (double)a0.z, d0); d0 = fma(dx3, (double)a0.w, d0);
            d1 = fma(dx0, (double)a1.x, d1); d1 = fma(dx1, (double)a1.y, d1);
            d1 = fma(dx2, (double)a1.z, d1); d1 = fma(dx3, (double)a1.w, d1);
            d2 = fma(dx0, (double)a2.x, d2); d2 = fma(dx1, (double)a2.y, d2);
            d2 = fma(dx2, (double)a2.z, d2); d2 = fma(dx3, (double)a2.w, d2);
            d3 = fma(dx0, (double)a3.x, d3); d3 = fma(dx1, (double)a3.y, d3);
            d3 = fma(dx2, (double)a3.z, d3); d3 = fma(dx3, (double)a3.w, d3);
        }
#pragma unroll
        for (int off = 32; off; off >>= 1) {
            d0 += __shfl_xor(d0, off, 64);
            d1 += __shfl_xor(d1, off, 64);
            d2 += __shfl_xor(d2, off, 64);
            d3 += __shfl_xor(d3, off, 64);
        }

        double bd[4] = {d0, d1, d2, d3};
        // ordered top-2 among (bd[r], cand[r]): desc value, tie -> asc index
        int e1 = cand[0]; double l1 = bd[0];
#pragma unroll
        for (int r = 1; r < 4; ++r)
            if (bd[r] > l1 || (bd[r] == l1 && cand[r] < e1)) { l1 = bd[r]; e1 = cand[r]; }
        int e2 = -1; double l2 = -1e300;
#pragma unroll
        for (int r = 0; r < 4; ++r) {
            if (cand[r] == e1) continue;
            if (e2 < 0 || bd[r] > l2 || (bd[r] == l2 && cand[r] < e2)) { l2 = bd[r]; e2 = cand[r]; }
        }

        // normalized top-2 weights: softmax denominator cancels
        double rr = exp(l2 - l1);            // l2 <= l1
        double w1 = 1.0 / (1.0 + rr);

        if (lane == 0) {
            const int gt = tok0 + t;
            out_idx[gt * 2]     = (float)e1;
            out_idx[gt * 2 + 1] = (float)e2;
            out_w[gt * 2]       = (float)w1;
            out_w[gt * 2 + 1]   = (float)(1.0 - w1);
            atomicAdd(&g_cnt[b * EE + e1], 1.0f);
            atomicAdd(&g_cnt[b * EE + e2], 1.0f);
        }
    }

    atomicAdd(&bssum[lane], my_ssum);
    __syncthreads();
    if (tid < EE) atomicAdd(&g_ssum[b * EE + tid], bssum[tid]);
}

// K2: aux = 0.01/(B * 128 * S) * sum_{b,e} cnt[b,e]*ssum[b,e]   (E/(S*K)=1/128)
__global__ void finalize(const float* __restrict__ g_cnt,
                         const float* __restrict__ g_ssum,
                         float* __restrict__ aux_out) {
    int lane = threadIdx.x;  // 64 threads
    float a = 0.f;
    for (int b = 0; b < BB; ++b) a += g_cnt[b * EE + lane] * g_ssum[b * EE + lane];
#pragma unroll
    for (int off = 32; off; off >>= 1) a += __shfl_xor(a, off, 64);
    if (lane == 0) aux_out[0] = a * (0.01f / (4.f * 128.f * 4096.f));
}

extern "C" void kernel_launch(void* const* d_in, const int* in_sizes, int n_in,
                              void* d_out, int out_size, void* d_ws, size_t ws_size,
                              hipStream_t stream) {
    const float* x = (const float*)d_in[0];   // [4,4096,2048]
    const float* w = (const float*)d_in[1];   // [64,2048]
    float* out = (float*)d_out;
    float* out_idx = out;                 // [16384*2]
    float* out_w   = out + 2 * TT;        // [16384*2]
    float* aux     = out + 4 * TT;        // [1]

    v2f*   wt2    = (v2f*)d_ws;                        // 512 KB paired transposed weight
    float* g_cnt  = (float*)d_ws + (size_t)HH * EE;    // 256 floats
    float* g_ssum = g_cnt + BB * EE;                   // 256 floats

    hipMemsetAsync(g_cnt, 0, 2 * BB * EE * sizeof(float), stream);
    transpose_w<<<(HH * EE / 2) / 256, 256, 0, stream>>>(w, wt2);
    moe_gate<<<TT / M_TOK, 256, 0, stream>>>(x, w, wt2, out_idx, out_w, g_cnt, g_ssum);
    finalize<<<1, 64, 0, stream>>>(g_cnt, g_ssum, aux);
}

// Round 3
// 310.961 us; speedup vs baseline: 2.0702x; 2.0702x over previous
//
#include <hip/hip_runtime.h>
#include <math.h>

// MoE gate: B=4, S=4096, H=2048, E=64, top-2, seq_aux loss.
// d_out layout (float): topk_idx [16384*2] | topk_weight [16384*2] | aux_loss [1]
//
// Phase 1 (GEMM 16384x64x2048) runs on MFMA via bf16 hi/lo split:
//   x = hi + lo (each bf16, RN), logits ~= Ahi*Bhi + Ahi*Blo + Alo*Bhi  (err ~3e-6)
// Phase 2: fp32 softmax (aux), fp32 top-4 candidates, fp64 exact re-rank -> top-2.

#define TT 16384
#define HH 2048
#define EE 64
#define BB 4
#define M_TOK 16   // tokens per block (one MFMA M-tile)
#define KCH 256    // k per LDS chunk
#define TPW 4      // tokens per wave in phase 2

typedef float v2f __attribute__((ext_vector_type(2)));
typedef float v4f __attribute__((ext_vector_type(4)));
typedef float f4v __attribute__((ext_vector_type(4)));
typedef short s8v __attribute__((ext_vector_type(8)));

__device__ __forceinline__ unsigned short f2bf(float f) {
    unsigned u = __float_as_uint(f);
    return (unsigned short)((u + 0x7fffu + ((u >> 16) & 1u)) >> 16);
}
__device__ __forceinline__ float bf2f(unsigned short h) {
    return __uint_as_float(((unsigned)h) << 16);
}

// Pre-pack W[E][H] into MFMA B-fragment order, bf16 hi/lo:
// b[nt][ks][lane][j] = w[nt*16 + (lane&15)][ks*32 + (lane>>4)*8 + j]
__global__ void prep_b(const float* __restrict__ w,
                       unsigned short* __restrict__ bhi,
                       unsigned short* __restrict__ blo) {
    int idx = blockIdx.x * blockDim.x + threadIdx.x;   // 0..131071
    int j    = idx & 7;
    int lane = (idx >> 3) & 63;
    int ks   = (idx >> 9) & 63;
    int nt   = idx >> 15;
    int e = nt * 16 + (lane & 15);
    int k = ks * 32 + (lane >> 4) * 8 + j;
    float f = w[e * HH + k];
    unsigned short h = f2bf(f);
    bhi[idx] = h;
    blo[idx] = f2bf(f - bf2f(h));
}

__global__ __launch_bounds__(256) void moe_gate(
    const float* __restrict__ x, const float* __restrict__ w,
    const unsigned short* __restrict__ bhi, const unsigned short* __restrict__ blo,
    float* __restrict__ out_idx, float* __restrict__ out_w,
    float* __restrict__ g_cnt, float* __restrict__ g_ssum) {

    __shared__ unsigned short ahi[8 * 64 * 8];  // [kstep][entry][8] bf16 = 8 KB
    __shared__ unsigned short alo[8 * 64 * 8];  // 8 KB
    __shared__ float part[M_TOK][EE + 1];       // final logits, padded stride
    __shared__ float bssum[EE];

    const int tid  = threadIdx.x;
    const int wave = tid >> 6;                  // = N-tile (16 experts)
    const int lane = tid & 63;
    const int tok0 = blockIdx.x * M_TOK;
    const int b    = tok0 >> 12;                // batch (uniform: 16 | 4096)

    if (tid < EE) bssum[tid] = 0.f;

    const int m  = tid >> 4;                    // staging: token row 0..15
    const int kb = tid & 15;

    f4v acc = {0.f, 0.f, 0.f, 0.f};

    // ---------------- phase 1: K-chunked MFMA GEMM ----------------
    for (int c = 0; c < 8; ++c) {
        __syncthreads();   // previous chunk's LDS reads done
        // stage 16 tok x 256 k fp32 -> bf16 hi/lo in A-fragment LDS layout
#pragma unroll
        for (int g = 0; g < 2; ++g) {
            const int k8i = kb + g * 16;        // 8-float group 0..31
            const float* __restrict__ xp =
                x + (size_t)(tok0 + m) * HH + c * KCH + k8i * 8;
            v4f x0 = *(const v4f*)xp;
            v4f x1 = *(const v4f*)(xp + 4);
            float xs[8] = {x0.x, x0.y, x0.z, x0.w, x1.x, x1.y, x1.z, x1.w};
            s8v hv, lv;
#pragma unroll
            for (int j = 0; j < 8; ++j) {
                unsigned short h = f2bf(xs[j]);
                hv[j] = (short)h;
                lv[j] = (short)f2bf(xs[j] - bf2f(h));
            }
            const int kstep = k8i >> 2, quad = k8i & 3;
            const int entry = kstep * 64 + quad * 16 + (m ^ (quad << 1)); // swizzle
            *(s8v*)&ahi[entry * 8] = hv;
            *(s8v*)&alo[entry * 8] = lv;
        }
        __syncthreads();
        // compute: wave owns N-tile `wave`, 8 K-steps of 32
        const int rdentry_base = lane ^ ((lane >> 4) << 1);
#pragma unroll
        for (int ks = 0; ks < 8; ++ks) {
            const int entry = ks * 64 + rdentry_base;
            s8v af_h = *(const s8v*)&ahi[entry * 8];
            s8v af_l = *(const s8v*)&alo[entry * 8];
            const size_t boff = ((size_t)(wave * 64 + c * 8 + ks) * 64 + lane) * 8;
            s8v bf_h = *(const s8v*)&bhi[boff];
            s8v bf_l = *(const s8v*)&blo[boff];
            acc = __builtin_amdgcn_mfma_f32_16x16x32_bf16(af_h, bf_h, acc, 0, 0, 0);
            acc = __builtin_amdgcn_mfma_f32_16x16x32_bf16(af_h, bf_l, acc, 0, 0, 0);
            acc = __builtin_amdgcn_mfma_f32_16x16x32_bf16(af_l, bf_h, acc, 0, 0, 0);
        }
    }
    __syncthreads();
    // C-layout: col = lane&15 (expert in tile), row = (lane>>4)*4 + r (token)
#pragma unroll
    for (int r = 0; r < 4; ++r)
        part[(lane >> 4) * 4 + r][wave * 16 + (lane & 15)] = acc[r];
    __syncthreads();

    // ---------- phase 2+3: softmax, fp32 top-4, fp64 re-rank ----------
    float my_ssum = 0.f;
    for (int ti = 0; ti < TPW; ++ti) {
        const int t = wave * TPW + ti;
        float logit = part[t][lane];

        float mx = logit;
#pragma unroll
        for (int off = 32; off; off >>= 1) mx = fmaxf(mx, __shfl_xor(mx, off, 64));
        float p = __expf(logit - mx);
        float Z = p;
#pragma unroll
        for (int off = 32; off; off >>= 1) Z += __shfl_xor(Z, off, 64);
        my_ssum += p / Z;

        // top-4 candidates by fp32 logit (tie -> lower index)
        float v = logit;
        int cand[4];
#pragma unroll
        for (int r = 0; r < 4; ++r) {
            float bv = v; int bi = lane;
#pragma unroll
            for (int off = 32; off; off >>= 1) {
                float ov = __shfl_xor(bv, off, 64);
                int   oi = __shfl_xor(bi, off, 64);
                if (ov > bv || (ov == bv && oi < bi)) { bv = ov; bi = oi; }
            }
            cand[r] = bi;
            if (lane == bi) v = -3.4e38f;
        }

        // fp64 re-rank: 64 lanes cooperate, float4 x 8 strided
        const float* __restrict__ xt  = x + (size_t)(tok0 + t) * HH;
        const float* __restrict__ w0p = w + (size_t)cand[0] * HH;
        const float* __restrict__ w1p = w + (size_t)cand[1] * HH;
        const float* __restrict__ w2p = w + (size_t)cand[2] * HH;
        const float* __restrict__ w3p = w + (size_t)cand[3] * HH;
        double d0 = 0.0, d1 = 0.0, d2 = 0.0, d3 = 0.0;
#pragma unroll
        for (int i = 0; i < 8; ++i) {
            const int k = i * 256 + lane * 4;
            v4f xv = *(const v4f*)(xt + k);
            v4f a0 = *(const v4f*)(w0p + k);
            v4f a1 = *(const v4f*)(w1p + k);
            v4f a2 = *(const v4f*)(w2p + k);
            v4f a3 = *(const v4f*)(w3p + k);
            double dx0 = (double)xv.x, dx1 = (double)xv.y;
            double dx2 = (double)xv.z, dx3 = (double)xv.w;
            d0 = fma(dx0, (double)a0.x, d0); d0 = fma(dx1, (double)a0.y, d0);
            d0 = fma(dx2, (double)a0.z, d0); d0 = fma(dx3, (double)a0.w, d0);
            d1 = fma(dx0, (double)a1.x, d1); d1 = fma(dx1, (double)a1.y, d1);
            d1 = fma(dx2, (double)a1.z, d1); d1 = fma(dx3, (double)a1.w, d1);
            d2 = fma(dx0, (double)a2.x, d2); d2 = fma(dx1, (double)a2.y, d2);
            d2 = fma(dx2, (double)a2.z, d2); d2 = fma(dx3, (double)a2.w, d2);
            d3 = fma(dx0, (double)a3.x, d3); d3 = fma(dx1, (double)a3.y, d3);
            d3 = fma(dx2, (double)a3.z, d3); d3 = fma(dx3, (double)a3.w, d3);
        }
#pragma unroll
        for (int off = 32; off; off >>= 1) {
            d0 += __shfl_xor(d0, off, 64);
            d1 += __shfl_xor(d1, off, 64);
            d2 += __shfl_xor(d2, off, 64);
            d3 += __shfl_xor(d3, off, 64);
        }

        double bd[4] = {d0, d1, d2, d3};
        int e1 = cand[0]; double l1 = bd[0];
#pragma unroll
        for (int r = 1; r < 4; ++r)
            if (bd[r] > l1 || (bd[r] == l1 && cand[r] < e1)) { l1 = bd[r]; e1 = cand[r]; }
        int e2 = -1; double l2 = -1e300;
#pragma unroll
        for (int r = 0; r < 4; ++r) {
            if (cand[r] == e1) continue;
            if (e2 < 0 || bd[r] > l2 || (bd[r] == l2 && cand[r] < e2)) { l2 = bd[r]; e2 = cand[r]; }
        }

        double rr = exp(l2 - l1);
        double w1 = 1.0 / (1.0 + rr);

        if (lane == 0) {
            const int gt = tok0 + t;
            out_idx[gt * 2]     = (float)e1;
            out_idx[gt * 2 + 1] = (float)e2;
            out_w[gt * 2]       = (float)w1;
            out_w[gt * 2 + 1]   = (float)(1.0 - w1);
            atomicAdd(&g_cnt[b * EE + e1], 1.0f);
            atomicAdd(&g_cnt[b * EE + e2], 1.0f);
        }
    }

    atomicAdd(&bssum[lane], my_ssum);
    __syncthreads();
    if (tid < EE) atomicAdd(&g_ssum[b * EE + tid], bssum[tid]);
}

// aux = 0.01/(B * 128 * S) * sum_{b,e} cnt[b,e]*ssum[b,e]   (E/(S*K)=1/128)
__global__ void finalize(const float* __restrict__ g_cnt,
                         const float* __restrict__ g_ssum,
                         float* __restrict__ aux_out) {
    int lane = threadIdx.x;  // 64 threads
    float a = 0.f;
    for (int b = 0; b < BB; ++b) a += g_cnt[b * EE + lane] * g_ssum[b * EE + lane];
#pragma unroll
    for (int off = 32; off; off >>= 1) a += __shfl_xor(a, off, 64);
    if (lane == 0) aux_out[0] = a * (0.01f / (4.f * 128.f * 4096.f));
}

extern "C" void kernel_launch(void* const* d_in, const int* in_sizes, int n_in,
                              void* d_out, int out_size, void* d_ws, size_t ws_size,
                              hipStream_t stream) {
    const float* x = (const float*)d_in[0];   // [4,4096,2048]
    const float* w = (const float*)d_in[1];   // [64,2048]
    float* out = (float*)d_out;
    float* out_idx = out;                 // [16384*2]
    float* out_w   = out + 2 * TT;        // [16384*2]
    float* aux     = out + 4 * TT;        // [1]

    unsigned short* bhi = (unsigned short*)d_ws;          // 256 KB
    unsigned short* blo = bhi + (size_t)EE * HH;          // 256 KB
    float* g_cnt  = (float*)(blo + (size_t)EE * HH);      // 256 floats
    float* g_ssum = g_cnt + BB * EE;                      // 256 floats

    hipMemsetAsync(g_cnt, 0, 2 * BB * EE * sizeof(float), stream);
    prep_b<<<(EE * HH) / 256, 256, 0, stream>>>(w, bhi, blo);
    moe_gate<<<TT / M_TOK, 256, 0, stream>>>(x, w, bhi, blo, out_idx, out_w,
                                             g_cnt, g_ssum);
    finalize<<<1, 64, 0, stream>>>(g_cnt, g_ssum, aux);
}

// Round 4
// 245.852 us; speedup vs baseline: 2.6185x; 1.2648x over previous
//
#include <hip/hip_runtime.h>
#include <math.h>

// MoE gate: B=4, S=4096, H=2048, E=64, top-2, seq_aux loss.
// d_out layout (float): topk_idx [16384*2] | topk_weight [16384*2] | aux_loss [1]
//
// K1 gemm_logits: MFMA GEMM (bf16 hi/lo 3-term split, err <= ~1e-5) -> logits in ws.
// K2 gate_topk:  wave-per-token softmax/top-4/aux; flags tokens with fp32 gap < TAU.
// K3 rerank_exact: fp64 re-rank of flagged tokens only (~2-4%), overwrites outputs.

#define TT 16384
#define HH 2048
#define EE 64
#define BB 4
#define M_TOK 16   // tokens per GEMM block
#define KCH 256    // k per LDS chunk
#define TAU 2e-3f  // gap threshold: >> 100x the bf16-split logit error bound
#define NREP 8     // atomic replication for aux accumulators

typedef float v4f __attribute__((ext_vector_type(4)));
typedef float f4v __attribute__((ext_vector_type(4)));
typedef short s8v __attribute__((ext_vector_type(8)));

__device__ __forceinline__ unsigned short f2bf(float f) {
    unsigned u = __float_as_uint(f);
    return (unsigned short)((u + 0x7fffu + ((u >> 16) & 1u)) >> 16);
}
__device__ __forceinline__ float bf2f(unsigned short h) {
    return __uint_as_float(((unsigned)h) << 16);
}

// Pre-pack W[E][H] into MFMA B-fragment order, bf16 hi/lo:
// b[nt][ks][lane][j] = w[nt*16 + (lane&15)][ks*32 + (lane>>4)*8 + j]
__global__ void prep_b(const float* __restrict__ w,
                       unsigned short* __restrict__ bhi,
                       unsigned short* __restrict__ blo) {
    int idx = blockIdx.x * blockDim.x + threadIdx.x;   // 0..131071
    int j    = idx & 7;
    int lane = (idx >> 3) & 63;
    int ks   = (idx >> 9) & 63;
    int nt   = idx >> 15;
    int e = nt * 16 + (lane & 15);
    int k = ks * 32 + (lane >> 4) * 8 + j;
    float f = w[e * HH + k];
    unsigned short h = f2bf(f);
    bhi[idx] = h;
    blo[idx] = f2bf(f - bf2f(h));
}

// ---------------- K1: MFMA GEMM -> logits[TT][EE] ----------------
__global__ __launch_bounds__(256) void gemm_logits(
    const float* __restrict__ x,
    const unsigned short* __restrict__ bhi, const unsigned short* __restrict__ blo,
    float* __restrict__ logits) {

    __shared__ unsigned short ahi[2][8 * 64 * 8];  // 2 x 8 KB
    __shared__ unsigned short alo[2][8 * 64 * 8];  // 2 x 8 KB

    const int tid  = threadIdx.x;
    const int wave = tid >> 6;                  // N-tile (16 experts)
    const int lane = tid & 63;
    const int tok0 = blockIdx.x * M_TOK;
    const int m  = tid >> 4;                    // staging token row 0..15
    const int kb = tid & 15;

    v4f rx[2][4];                               // 2 chunks in flight, 16 floats each

    auto LD = [&](int c, int s) {
        const float* __restrict__ xp = x + (size_t)(tok0 + m) * HH + c * KCH + kb * 8;
        rx[s][0] = *(const v4f*)xp;
        rx[s][1] = *(const v4f*)(xp + 4);
        rx[s][2] = *(const v4f*)(xp + 128);
        rx[s][3] = *(const v4f*)(xp + 132);
    };
    auto ST = [&](int s, int bi) {
#pragma unroll
        for (int g = 0; g < 2; ++g) {
            v4f a = rx[s][g * 2], b2 = rx[s][g * 2 + 1];
            float xs[8] = {a.x, a.y, a.z, a.w, b2.x, b2.y, b2.z, b2.w};
            s8v hv, lv;
#pragma unroll
            for (int j = 0; j < 8; ++j) {
                unsigned short h = f2bf(xs[j]);
                hv[j] = (short)h;
                lv[j] = (short)f2bf(xs[j] - bf2f(h));
            }
            const int k8i = kb + g * 16;
            const int kstep = k8i >> 2, quad = k8i & 3;
            const int entry = kstep * 64 + quad * 16 + (m ^ (quad << 1)); // swizzle
            *(s8v*)&ahi[bi][entry * 8] = hv;
            *(s8v*)&alo[bi][entry * 8] = lv;
        }
    };

    LD(0, 0);
    LD(1, 1);
    ST(0, 0);
    __syncthreads();

    f4v acc = {0.f, 0.f, 0.f, 0.f};
    const int rdl = lane ^ ((lane >> 4) << 1);  // swizzled read lane

#pragma unroll
    for (int c = 0; c < 8; ++c) {
        const int cur = c & 1;
        if (c < 6) LD(c + 2, cur);              // prefetch 2 chunks ahead
        if (c < 7) ST(cur ^ 1, cur ^ 1);        // stage chunk c+1 into other buffer
#pragma unroll
        for (int ks = 0; ks < 8; ++ks) {
            const int entry = ks * 64 + rdl;
            s8v af_h = *(const s8v*)&ahi[cur][entry * 8];
            s8v af_l = *(const s8v*)&alo[cur][entry * 8];
            const size_t boff = ((size_t)(wave * 64 + c * 8 + ks) * 64 + lane) * 8;
            s8v bf_h = *(const s8v*)&bhi[boff];
            s8v bf_l = *(const s8v*)&blo[boff];
            acc = __builtin_amdgcn_mfma_f32_16x16x32_bf16(af_h, bf_h, acc, 0, 0, 0);
            acc = __builtin_amdgcn_mfma_f32_16x16x32_bf16(af_h, bf_l, acc, 0, 0, 0);
            acc = __builtin_amdgcn_mfma_f32_16x16x32_bf16(af_l, bf_h, acc, 0, 0, 0);
        }
        __syncthreads();                        // one barrier per chunk (dbuf)
    }

    // C-layout: col = lane&15 (expert in tile), row = (lane>>4)*4 + r (token)
#pragma unroll
    for (int r = 0; r < 4; ++r)
        logits[(size_t)(tok0 + (lane >> 4) * 4 + r) * EE + wave * 16 + (lane & 15)] = acc[r];
}

// ---------------- K2: wave-per-token topk/softmax/aux + flag ----------------
__global__ __launch_bounds__(256) void gate_topk(
    const float* __restrict__ logits,
    float* __restrict__ out_idx, float* __restrict__ out_w,
    float* __restrict__ g_cnt, float* __restrict__ g_ssum,
    int* __restrict__ wl_cnt, int* __restrict__ wl) {

    __shared__ float bssum[EE];
    const int tid  = threadIdx.x;
    const int lane = tid & 63;
    const int t    = blockIdx.x * 4 + (tid >> 6);
    const int rep  = (blockIdx.x & (NREP - 1)) * (BB * EE);

    if (tid < EE) bssum[tid] = 0.f;

    float l = logits[(size_t)t * EE + lane];

    // softmax score (fp32, feeds aux only)
    float mx = l;
#pragma unroll
    for (int off = 32; off; off >>= 1) mx = fmaxf(mx, __shfl_xor(mx, off, 64));
    float p = __expf(l - mx);
    float Z = p;
#pragma unroll
    for (int off = 32; off; off >>= 1) Z += __shfl_xor(Z, off, 64);
    float s = p / Z;

    // top-4 by fp32 logit (tie -> lower index)
    float v = l;
    int cand[4]; float cl[4];
#pragma unroll
    for (int r = 0; r < 4; ++r) {
        float bv = v; int bi = lane;
#pragma unroll
        for (int off = 32; off; off >>= 1) {
            float ov = __shfl_xor(bv, off, 64);
            int   oi = __shfl_xor(bi, off, 64);
            if (ov > bv || (ov == bv && oi < bi)) { bv = ov; bi = oi; }
        }
        cand[r] = bi; cl[r] = bv;
        if (lane == bi) v = -3.4e38f;
    }

    __syncthreads();
    atomicAdd(&bssum[lane], s);

    if (lane == 0) {
        const int b = t >> 12;
        atomicAdd(&g_cnt[rep + b * EE + cand[0]], 1.f);
        atomicAdd(&g_cnt[rep + b * EE + cand[1]], 1.f);
        float w1 = 1.f / (1.f + __expf(cl[1] - cl[0]));  // softmax denom cancels
        out_idx[t * 2]     = (float)cand[0];
        out_idx[t * 2 + 1] = (float)cand[1];
        out_w[t * 2]       = w1;
        out_w[t * 2 + 1]   = 1.f - w1;
        if (cl[0] - cl[1] < TAU || cl[1] - cl[2] < TAU) {
            int pos = atomicAdd(wl_cnt, 1);
            wl[pos] = t;
        }
    }

    __syncthreads();
    if (tid < EE) {
        const int b0 = (blockIdx.x * 4) >> 12;  // block-uniform batch
        atomicAdd(&g_ssum[rep + b0 * EE + tid], bssum[tid]);
    }
}

// ---------------- K3: fp64 exact re-rank of flagged tokens ----------------
__global__ __launch_bounds__(256) void rerank_exact(
    const float* __restrict__ logits, const float* __restrict__ x,
    const float* __restrict__ w,
    const int* __restrict__ wl_cnt, const int* __restrict__ wl,
    float* __restrict__ out_idx, float* __restrict__ out_w) {

    const int lane = threadIdx.x & 63;
    const int wid  = blockIdx.x * 4 + (threadIdx.x >> 6);
    const int n    = wl_cnt[0];

    for (int i = wid; i < n; i += 32 * 4) {
        const int t = wl[i];
        float l = logits[(size_t)t * EE + lane];

        float v = l;
        int cand[4];
#pragma unroll
        for (int r = 0; r < 4; ++r) {
            float bv = v; int bi = lane;
#pragma unroll
            for (int off = 32; off; off >>= 1) {
                float ov = __shfl_xor(bv, off, 64);
                int   oi = __shfl_xor(bi, off, 64);
                if (ov > bv || (ov == bv && oi < bi)) { bv = ov; bi = oi; }
            }
            cand[r] = bi;
            if (lane == bi) v = -3.4e38f;
        }

        const float* __restrict__ xt  = x + (size_t)t * HH;
        const float* __restrict__ w0p = w + (size_t)cand[0] * HH;
        const float* __restrict__ w1p = w + (size_t)cand[1] * HH;
        const float* __restrict__ w2p = w + (size_t)cand[2] * HH;
        const float* __restrict__ w3p = w + (size_t)cand[3] * HH;
        double d0 = 0.0, d1 = 0.0, d2 = 0.0, d3 = 0.0;
#pragma unroll
        for (int ii = 0; ii < 8; ++ii) {
            const int k = ii * 256 + lane * 4;
            v4f xv = *(const v4f*)(xt + k);
            v4f a0 = *(const v4f*)(w0p + k);
            v4f a1 = *(const v4f*)(w1p + k);
            v4f a2 = *(const v4f*)(w2p + k);
            v4f a3 = *(const v4f*)(w3p + k);
            double dx0 = (double)xv.x, dx1 = (double)xv.y;
            double dx2 = (double)xv.z, dx3 = (double)xv.w;
            d0 = fma(dx0, (double)a0.x, d0); d0 = fma(dx1, (double)a0.y, d0);
            d0 = fma(dx2, (double)a0.z, d0); d0 = fma(dx3, (double)a0.w, d0);
            d1 = fma(dx0, (double)a1.x, d1); d1 = fma(dx1, (double)a1.y, d1);
            d1 = fma(dx2, (double)a1.z, d1); d1 = fma(dx3, (double)a1.w, d1);
            d2 = fma(dx0, (double)a2.x, d2); d2 = fma(dx1, (double)a2.y, d2);
            d2 = fma(dx2, (double)a2.z, d2); d2 = fma(dx3, (double)a2.w, d2);
            d3 = fma(dx0, (double)a3.x, d3); d3 = fma(dx1, (double)a3.y, d3);
            d3 = fma(dx2, (double)a3.z, d3); d3 = fma(dx3, (double)a3.w, d3);
        }
#pragma unroll
        for (int off = 32; off; off >>= 1) {
            d0 += __shfl_xor(d0, off, 64);
            d1 += __shfl_xor(d1, off, 64);
            d2 += __shfl_xor(d2, off, 64);
            d3 += __shfl_xor(d3, off, 64);
        }

        double bd[4] = {d0, d1, d2, d3};
        int e1 = cand[0]; double l1 = bd[0];
#pragma unroll
        for (int r = 1; r < 4; ++r)
            if (bd[r] > l1 || (bd[r] == l1 && cand[r] < e1)) { l1 = bd[r]; e1 = cand[r]; }
        int e2 = -1; double l2 = -1e300;
#pragma unroll
        for (int r = 0; r < 4; ++r) {
            if (cand[r] == e1) continue;
            if (e2 < 0 || bd[r] > l2 || (bd[r] == l2 && cand[r] < e2)) { l2 = bd[r]; e2 = cand[r]; }
        }

        double w1 = 1.0 / (1.0 + exp(l2 - l1));
        if (lane == 0) {
            out_idx[t * 2]     = (float)e1;
            out_idx[t * 2 + 1] = (float)e2;
            out_w[t * 2]       = (float)w1;
            out_w[t * 2 + 1]   = (float)(1.0 - w1);
        }
    }
}

// aux = 0.01/(B * 128 * S) * sum_{b,e} cnt[b,e]*ssum[b,e]   (E/(S*K)=1/128)
__global__ void finalize(const float* __restrict__ g_cnt,
                         const float* __restrict__ g_ssum,
                         float* __restrict__ aux_out) {
    int lane = threadIdx.x;  // 64 threads, lane = expert
    float a = 0.f;
    for (int b = 0; b < BB; ++b) {
        float c = 0.f, ss = 0.f;
#pragma unroll
        for (int r = 0; r < NREP; ++r) {
            c  += g_cnt[r * (BB * EE) + b * EE + lane];
            ss += g_ssum[r * (BB * EE) + b * EE + lane];
        }
        a += c * ss;
    }
#pragma unroll
    for (int off = 32; off; off >>= 1) a += __shfl_xor(a, off, 64);
    if (lane == 0) aux_out[0] = a * (0.01f / (4.f * 128.f * 4096.f));
}

extern "C" void kernel_launch(void* const* d_in, const int* in_sizes, int n_in,
                              void* d_out, int out_size, void* d_ws, size_t ws_size,
                              hipStream_t stream) {
    const float* x = (const float*)d_in[0];   // [4,4096,2048]
    const float* w = (const float*)d_in[1];   // [64,2048]
    float* out = (float*)d_out;
    float* out_idx = out;                 // [16384*2]
    float* out_w   = out + 2 * TT;        // [16384*2]
    float* aux     = out + 4 * TT;        // [1]

    // ws layout
    float* logits = (float*)d_ws;                                   // 4 MB
    unsigned short* bhi = (unsigned short*)(logits + (size_t)TT * EE); // 256 KB
    unsigned short* blo = bhi + (size_t)EE * HH;                    // 256 KB
    float* g_cnt  = (float*)(blo + (size_t)EE * HH);                // 8 KB
    float* g_ssum = g_cnt + NREP * BB * EE;                         // 8 KB
    int*   wl_cnt = (int*)(g_ssum + NREP * BB * EE);                // 64 B
    int*   wl     = wl_cnt + 16;                                    // 64 KB

    hipMemsetAsync(g_cnt, 0, (2 * NREP * BB * EE + 16) * sizeof(float), stream);
    prep_b<<<(EE * HH) / 256, 256, 0, stream>>>(w, bhi, blo);
    gemm_logits<<<TT / M_TOK, 256, 0, stream>>>(x, bhi, blo, logits);
    gate_topk<<<TT / 4, 256, 0, stream>>>(logits, out_idx, out_w,
                                          g_cnt, g_ssum, wl_cnt, wl);
    rerank_exact<<<32, 256, 0, stream>>>(logits, x, w, wl_cnt, wl, out_idx, out_w);
    finalize<<<1, 64, 0, stream>>>(g_cnt, g_ssum, aux);
}